// Round 11
// baseline (1384.566 us; speedup 1.0000x reference)
//
#include <hip/hip_runtime.h>

#define NN 100000
#define EE 1600000
#define RRR 8
#define NSEG (NN*RRR)
#define F 128
#define BNEPS 1e-5f

typedef __attribute__((ext_vector_type(8))) short bf16x8;
typedef __attribute__((ext_vector_type(8))) unsigned short u16x8;
typedef __attribute__((ext_vector_type(4))) float f32x4;

static __device__ __forceinline__ unsigned short bf16r(float f) {
  unsigned u = __float_as_uint(f);
  u += 0x7fffu + ((u >> 16) & 1u);
  return (unsigned short)(u >> 16);
}
static __device__ __forceinline__ float b2f(unsigned short s) {
  return __uint_as_float((unsigned)s << 16);
}

// ------------------- preprocessing -------------------
__global__ void k_cnt(const int* __restrict__ dst, const int* __restrict__ et,
                      unsigned* __restrict__ cnt) {
  int e = blockIdx.x*256 + threadIdx.x;
  if (e < EE) atomicAdd(&cnt[dst[e]*RRR + et[e]], 1u);
}

__global__ void k_scan1(const unsigned* __restrict__ cnt, unsigned* __restrict__ off,
                        unsigned* __restrict__ bsum) {
  __shared__ unsigned s[256];
  int t = threadIdx.x;
  int base = blockIdx.x*2048 + t*8;
  unsigned loc[8];
  unsigned tot = 0;
#pragma unroll
  for (int j = 0; j < 8; j++) {
    unsigned v = (base+j < NSEG) ? cnt[base+j] : 0u;
    loc[j] = tot;
    tot += v;
  }
  s[t] = tot;
  __syncthreads();
  for (int d = 1; d < 256; d <<= 1) {
    unsigned v = (t >= d) ? s[t-d] : 0u;
    __syncthreads();
    s[t] += v;
    __syncthreads();
  }
  unsigned tbase = s[t] - tot;
#pragma unroll
  for (int j = 0; j < 8; j++)
    if (base+j < NSEG) off[base+j] = tbase + loc[j];
  if (t == 255) bsum[blockIdx.x] = s[255];
}

__global__ void k_scan2(unsigned* bsum, int nb) {
  __shared__ unsigned s[512];
  int t = threadIdx.x;
  unsigned v = (t < nb) ? bsum[t] : 0u;
  s[t] = v;
  __syncthreads();
  for (int d = 1; d < 512; d <<= 1) {
    unsigned u = (t >= d) ? s[t-d] : 0u;
    __syncthreads();
    s[t] += u;
    __syncthreads();
  }
  if (t < nb) bsum[t] = (t == 0) ? 0u : s[t-1];
}

__global__ void k_scan3(unsigned* off, const unsigned* __restrict__ bsum) {
  int i = blockIdx.x*256 + threadIdx.x;
  if (i < NSEG) off[i] += bsum[i >> 11];
}

// fill: off becomes segment END; start = off - cnt
__global__ void k_fill(const int* __restrict__ src, const int* __restrict__ dst,
                       const int* __restrict__ et, unsigned* __restrict__ off,
                       int* __restrict__ csr) {
  int e = blockIdx.x*256 + threadIdx.x;
  if (e < EE) {
    int seg = dst[e]*RRR + et[e];
    unsigned pos = atomicAdd(&off[seg], 1u);
    csr[pos] = src[e];
  }
}

// W' transposed: K = input channel (128), N-dim o = 1152 (8 rel tables + root).
// B-fragment layout: WB3[l][((kt*72 + ct)*64 + lane)*8 + j],
//   k = kt*32 + (lane>>4)*8 + j, o = ct*16 + (lane&15); rr = o>>7, oc = o&127.
__global__ void k_makeW3(const float* __restrict__ b1, const float* __restrict__ c1,
                         const float* __restrict__ r1, const float* __restrict__ b2,
                         const float* __restrict__ c2, const float* __restrict__ r2,
                         const float* __restrict__ b3, const float* __restrict__ c3,
                         const float* __restrict__ r3, unsigned short* __restrict__ WB3,
                         float* __restrict__ stats) {
  int kt = blockIdx.x, ct = blockIdx.y, l = blockIdx.z;
  int lane = threadIdx.x;
  if (kt == 0 && ct == 0 && l == 0) {
#pragma unroll
    for (int j = 0; j < 8; j++) stats[lane*8 + j] = 0.f;
  }
  const float* basis = (l == 0) ? b1 : (l == 1) ? b2 : b3;
  const float* comp  = (l == 0) ? c1 : (l == 1) ? c2 : c3;
  const float* root  = (l == 0) ? r1 : (l == 1) ? r2 : r3;
  int o = ct*16 + (lane & 15);
  int rr = o >> 7, oc = o & 127;
  int kbase = kt*32 + (lane >> 4)*8;
  unsigned short v[8];
#pragma unroll
  for (int j = 0; j < 8; j++) {
    int k = kbase + j;
    float val;
    if (rr < 8) {
      val = 0.f;
#pragma unroll
      for (int bb = 0; bb < 8; bb++)
        val += comp[rr*8+bb] * basis[(bb*F + k)*F + oc];
    } else {
      val = root[k*F + oc];
    }
    v[j] = bf16r(val);
  }
  unsigned short* dstp = WB3 + (size_t)l*(F*1152) + ((size_t)(kt*72 + ct)*64 + lane)*8;
#pragma unroll
  for (int j = 0; j < 8; j++) dstp[j] = v[j];
}

// BN affine consts
__global__ void k_scsh(const float* __restrict__ stats, const float* __restrict__ gamma,
                       const float* __restrict__ beta, float* __restrict__ scsh) {
  int c = threadIdx.x;
  const float invN = 1.f/(float)NN;
  float m = stats[c]*invN;
  float var = stats[128+c]*invN - m*m;
  float rs = rsqrtf(var + BNEPS);
  float g = gamma[c]*rs;
  scsh[c] = g;
  scsh[128+c] = beta[c] - m*g;
}

// ------------------- dense GEMM: Y[ct0/8 .. ct1/8) = act(bn(in)) @ W'[:, range] ----
// Block 256 = 4 waves; wave = 32 rows. A-frags loaded once (BN+LeakyReLU inline
// for l>0), B streamed from L2. Y tables bf16 [rr-tb0][node][128].
__global__ __launch_bounds__(256) void k_gemmY(const float* __restrict__ xin,
    const unsigned short* __restrict__ cin, const float* __restrict__ scsh,
    const unsigned short* __restrict__ WB, unsigned short* __restrict__ Yb,
    int useF32, int ct0, int ct1, int tb0) {
  int t = threadIdx.x;
  int wave = t >> 6, lane = t & 63;
  int rlo = lane & 15, kg = lane >> 4;
  int rbase = (blockIdx.x*4 + wave)*32;
  int r0 = rbase + rlo;       if (r0 > NN-1) r0 = NN-1;
  int r1 = rbase + 16 + rlo;  if (r1 > NN-1) r1 = NN-1;

  bf16x8 a0[4], a1[4];
#pragma unroll
  for (int kt = 0; kt < 4; kt++) {
    int co = kt*32 + kg*8;
    u16x8 o0, o1;
    if (useF32) {
      const float* p0 = xin + (size_t)r0*F + co;
      const float* p1 = xin + (size_t)r1*F + co;
      float4 v0a = *(const float4*)p0, v0b = *(const float4*)(p0+4);
      float4 v1a = *(const float4*)p1, v1b = *(const float4*)(p1+4);
      o0[0]=bf16r(v0a.x); o0[1]=bf16r(v0a.y); o0[2]=bf16r(v0a.z); o0[3]=bf16r(v0a.w);
      o0[4]=bf16r(v0b.x); o0[5]=bf16r(v0b.y); o0[6]=bf16r(v0b.z); o0[7]=bf16r(v0b.w);
      o1[0]=bf16r(v1a.x); o1[1]=bf16r(v1a.y); o1[2]=bf16r(v1a.z); o1[3]=bf16r(v1a.w);
      o1[4]=bf16r(v1b.x); o1[5]=bf16r(v1b.y); o1[6]=bf16r(v1b.z); o1[7]=bf16r(v1b.w);
    } else {
      u16x8 v0 = *(const u16x8*)&cin[(size_t)r0*F + co];
      u16x8 v1 = *(const u16x8*)&cin[(size_t)r1*F + co];
      float4 sca = *(const float4*)&scsh[co], scb = *(const float4*)&scsh[co+4];
      float4 sha = *(const float4*)&scsh[128+co], shb = *(const float4*)&scsh[128+co+4];
      float sc[8] = {sca.x,sca.y,sca.z,sca.w,scb.x,scb.y,scb.z,scb.w};
      float sh[8] = {sha.x,sha.y,sha.z,sha.w,shb.x,shb.y,shb.z,shb.w};
#pragma unroll
      for (int j = 0; j < 8; j++) {
        float z0 = b2f(v0[j])*sc[j] + sh[j];
        float z1 = b2f(v1[j])*sc[j] + sh[j];
        o0[j] = bf16r(fmaxf(z0, 0.1f*z0));
        o1[j] = bf16r(fmaxf(z1, 0.1f*z1));
      }
    }
    a0[kt] = (bf16x8)o0;
    a1[kt] = (bf16x8)o1;
  }

  const unsigned short* bp = WB + (size_t)lane*8;
  for (int ct = ct0; ct < ct1; ct++) {
    f32x4 acc0 = (f32x4){0.f,0.f,0.f,0.f};
    f32x4 acc1 = (f32x4){0.f,0.f,0.f,0.f};
#pragma unroll
    for (int kt = 0; kt < 4; kt++) {
      bf16x8 b = *(const bf16x8*)(bp + (size_t)(kt*72 + ct)*512);
      acc0 = __builtin_amdgcn_mfma_f32_16x16x32_bf16(a0[kt], b, acc0, 0, 0, 0);
      acc1 = __builtin_amdgcn_mfma_f32_16x16x32_bf16(a1[kt], b, acc1, 0, 0, 0);
    }
    int rr = (ct >> 3) - tb0;
    int oc = (ct & 7)*16 + rlo;
    unsigned short* yb = Yb + (size_t)rr*NN*F + oc;
#pragma unroll
    for (int i = 0; i < 4; i++) {
      int n0 = rbase + kg*4 + i;
      int n1 = rbase + 16 + kg*4 + i;
      if (n0 < NN) yb[(size_t)n0*F] = bf16r(acc0[i]);
      if (n1 < NN) yb[(size_t)n1*F] = bf16r(acc1[i]);
    }
  }
}

// ------------------- aggregate pass: acc += sum_{r in pass} mean_r + (root) -------
// Block = 16 nodes; group g (16 lanes) = one node. first: seed with bias.
// !last: write f32 acc. last+mode0: bf16 cbuf + BN stats. last+mode1: L2norm->fout.
__global__ __launch_bounds__(256) void k_aggC(const unsigned short* __restrict__ Yb,
    const unsigned* __restrict__ off, const unsigned* __restrict__ cnt,
    const int* __restrict__ csr, const float* __restrict__ bias,
    unsigned short* __restrict__ cbuf, float* __restrict__ accb,
    float* __restrict__ fout, float* __restrict__ stats,
    int tb0, int ntab, int mode, int first, int last) {
  __shared__ float s_sum[128], s_sq[128];
  int t = threadIdx.x;
  int sl = t & 15, c8 = sl*8;
  int g = t >> 4;
  int lane = t & 63;
  int node = blockIdx.x*16 + g;
  if (mode == 0 && last && t < 128) { s_sum[t] = 0.f; s_sq[t] = 0.f; }

  float a[8];
  if (first) {
    float4 ba = *(const float4*)&bias[c8];
    float4 bb = *(const float4*)&bias[c8+4];
    a[0]=ba.x; a[1]=ba.y; a[2]=ba.z; a[3]=ba.w;
    a[4]=bb.x; a[5]=bb.y; a[6]=bb.z; a[7]=bb.w;
  } else {
    const float* ap = accb + (size_t)node*F + c8;
    float4 va = *(const float4*)ap;
    float4 vb = *(const float4*)(ap+4);
    a[0]=va.x; a[1]=va.y; a[2]=va.z; a[3]=va.w;
    a[4]=vb.x; a[5]=vb.y; a[6]=vb.z; a[7]=vb.w;
  }

  int rend = tb0 + ntab;
  int relEnd = (rend < 8) ? rend : 8;
  int r = tb0;
  while (r < relEnd) {
    if (r + 1 < relEnd) {   // paired 2-segment interleave
      int s0 = node*RRR + r;
      unsigned cA = cnt[s0], cB = cnt[s0+1];
      unsigned bA = off[s0] - cA, bB = off[s0+1] - cB;
      const unsigned short* tA = Yb + (size_t)(r - tb0)*NN*F + c8;
      const unsigned short* tB = tA + (size_t)NN*F;
      float sA[8], sB[8];
#pragma unroll
      for (int u = 0; u < 8; u++) { sA[u] = 0.f; sB[u] = 0.f; }
      unsigned jA = 0, jB = 0;
      while (jA < cA || jB < cB) {
        unsigned nA = cA - jA; if (nA > 2) nA = 2;
        unsigned nB = cB - jB; if (nB > 2) nB = 2;
        int i0 = 0, i1 = 0, i2 = 0, i3 = 0;
        if (nA > 0) i0 = csr[bA + jA];
        if (nA > 1) i1 = csr[bA + jA + 1];
        if (nB > 0) i2 = csr[bB + jB];
        if (nB > 1) i3 = csr[bB + jB + 1];
        if (nA > 0) {
          u16x8 v = *(const u16x8*)&tA[(size_t)i0*F];
#pragma unroll
          for (int u = 0; u < 8; u++) sA[u] += b2f(v[u]);
        }
        if (nA > 1) {
          u16x8 v = *(const u16x8*)&tA[(size_t)i1*F];
#pragma unroll
          for (int u = 0; u < 8; u++) sA[u] += b2f(v[u]);
        }
        if (nB > 0) {
          u16x8 v = *(const u16x8*)&tB[(size_t)i2*F];
#pragma unroll
          for (int u = 0; u < 8; u++) sB[u] += b2f(v[u]);
        }
        if (nB > 1) {
          u16x8 v = *(const u16x8*)&tB[(size_t)i3*F];
#pragma unroll
          for (int u = 0; u < 8; u++) sB[u] += b2f(v[u]);
        }
        jA += nA; jB += nB;
      }
      float ivA = cA ? 1.f/(float)cA : 0.f;
      float ivB = cB ? 1.f/(float)cB : 0.f;
#pragma unroll
      for (int u = 0; u < 8; u++) a[u] += sA[u]*ivA + sB[u]*ivB;
      r += 2;
    } else {                 // single segment, 2-at-a-time
      int s0 = node*RRR + r;
      unsigned cA = cnt[s0];
      unsigned bA = off[s0] - cA;
      const unsigned short* tA = Yb + (size_t)(r - tb0)*NN*F + c8;
      float sA[8];
#pragma unroll
      for (int u = 0; u < 8; u++) sA[u] = 0.f;
      unsigned j = 0;
      for (; j + 2 <= cA; j += 2) {
        int i0 = csr[bA + j];
        int i1 = csr[bA + j + 1];
        u16x8 v0 = *(const u16x8*)&tA[(size_t)i0*F];
        u16x8 v1 = *(const u16x8*)&tA[(size_t)i1*F];
#pragma unroll
        for (int u = 0; u < 8; u++) sA[u] += b2f(v0[u]) + b2f(v1[u]);
      }
      if (j < cA) {
        int i0 = csr[bA + j];
        u16x8 v0 = *(const u16x8*)&tA[(size_t)i0*F];
#pragma unroll
        for (int u = 0; u < 8; u++) sA[u] += b2f(v0[u]);
      }
      float ivA = cA ? 1.f/(float)cA : 0.f;
#pragma unroll
      for (int u = 0; u < 8; u++) a[u] += sA[u]*ivA;
      r += 1;
    }
  }
  if (rend > 8) {   // root/self table in this pass
    u16x8 v = *(const u16x8*)&Yb[((size_t)(8 - tb0)*NN + node)*F + c8];
#pragma unroll
    for (int u = 0; u < 8; u++) a[u] += b2f(v[u]);
  }

  if (!last) {
    float* ap = accb + (size_t)node*F + c8;
    *(float4*)ap     = make_float4(a[0], a[1], a[2], a[3]);
    *(float4*)(ap+4) = make_float4(a[4], a[5], a[6], a[7]);
  } else if (mode == 0) {
    u16x8 o;
#pragma unroll
    for (int u = 0; u < 8; u++) o[u] = bf16r(a[u]);
    *(u16x8*)&cbuf[(size_t)node*F + c8] = o;
    float ps[8], pq[8];
#pragma unroll
    for (int u = 0; u < 8; u++) { ps[u] = a[u]; pq[u] = a[u]*a[u]; }
#pragma unroll
    for (int u = 0; u < 8; u++) {
      ps[u] += __shfl_xor(ps[u], 16, 64); ps[u] += __shfl_xor(ps[u], 32, 64);
      pq[u] += __shfl_xor(pq[u], 16, 64); pq[u] += __shfl_xor(pq[u], 32, 64);
    }
    __syncthreads();
    if (lane < 16) {
#pragma unroll
      for (int u = 0; u < 8; u++) {
        atomicAdd(&s_sum[c8+u], ps[u]);
        atomicAdd(&s_sq [c8+u], pq[u]);
      }
    }
    __syncthreads();
    if (t < 128) {
      atomicAdd(&stats[t],       s_sum[t]);
      atomicAdd(&stats[128 + t], s_sq[t]);
    }
  } else {
    float ss = 0.f;
#pragma unroll
    for (int u = 0; u < 8; u++) ss += a[u]*a[u];
    ss += __shfl_xor(ss, 1, 64); ss += __shfl_xor(ss, 2, 64);
    ss += __shfl_xor(ss, 4, 64); ss += __shfl_xor(ss, 8, 64);
    float inv = 1.f / fmaxf(sqrtf(ss), 1e-12f);
    float* orow = fout + (size_t)node*F + c8;
    *(float4*)orow     = make_float4(a[0]*inv, a[1]*inv, a[2]*inv, a[3]*inv);
    *(float4*)(orow+4) = make_float4(a[4]*inv, a[5]*inv, a[6]*inv, a[7]*inv);
  }
}

// ------------------- host launcher -------------------
extern "C" void kernel_launch(void* const* d_in, const int* in_sizes, int n_in,
                              void* d_out, int out_size, void* d_ws, size_t ws_size,
                              hipStream_t stream) {
  const float* x      = (const float*)d_in[0];
  const int*   ei     = (const int*)d_in[1];
  const int*   etp    = (const int*)d_in[2];
  const float* basis[3] = {(const float*)d_in[3], (const float*)d_in[7],  (const float*)d_in[11]};
  const float* comp[3]  = {(const float*)d_in[4], (const float*)d_in[8],  (const float*)d_in[12]};
  const float* root[3]  = {(const float*)d_in[5], (const float*)d_in[9],  (const float*)d_in[13]};
  const float* bias[3]  = {(const float*)d_in[6], (const float*)d_in[10], (const float*)d_in[14]};
  const float* gamma[2] = {(const float*)d_in[15], (const float*)d_in[17]};
  const float* beta[2]  = {(const float*)d_in[16], (const float*)d_in[18]};
  const int* srcv = ei;
  const int* dstv = ei + EE;
  float* out = (float*)d_out;

  char* w = (char*)d_ws;
  size_t p = 0;
  auto take = [&](size_t bytes) -> void* {
    void* q = w + p;
    p = (p + bytes + 255) & ~(size_t)255;
    return q;
  };
  unsigned* cnt   = (unsigned*)take((size_t)NSEG*4);
  unsigned* off   = (unsigned*)take((size_t)NSEG*4);
  int*      csr   = (int*)     take((size_t)EE*4);
  unsigned* bsum  = (unsigned*)take(1024*4);
  unsigned short* WB3 = (unsigned short*)take((size_t)3*F*1152*2);
  float*    stats = (float*)   take(512*4);
  float*    scshb = (float*)   take(512*4);
  unsigned short* cbuf = (unsigned short*)take((size_t)NN*F*2);
  size_t avail = (ws_size > p) ? (ws_size - p) : 0;
  size_t tabBytes = (size_t)NN*F*2;
  int ntab = (int)(avail / tabBytes);
  if (ntab > 9) ntab = 9;
  if (ntab < 1) ntab = 1;
  unsigned short* Yb = (unsigned short*)(w + p);

  // -------- preprocessing --------
  hipMemsetAsync(cnt, 0, (size_t)NSEG*4, stream);
  k_cnt<<<(EE+255)/256, 256, 0, stream>>>(dstv, etp, cnt);
  int nb1 = (NSEG + 2047)/2048;
  k_scan1<<<nb1, 256, 0, stream>>>(cnt, off, bsum);
  k_scan2<<<1, 512, 0, stream>>>(bsum, nb1);
  k_scan3<<<(NSEG+255)/256, 256, 0, stream>>>(off, bsum);
  k_fill<<<(EE+255)/256, 256, 0, stream>>>(srcv, dstv, etp, off, csr);
  dim3 gw(4, 72, 3);
  k_makeW3<<<gw, 64, 0, stream>>>(basis[0], comp[0], root[0],
                                  basis[1], comp[1], root[1],
                                  basis[2], comp[2], root[2], WB3, stats);

  // -------- 3 layers (transform-first, ws-adaptive passes) --------
  int gemmBlocks = (NN + 127)/128;
  int aggBlocks  = NN/16;
  for (int l = 0; l < 3; l++) {
    const unsigned short* WB = WB3 + (size_t)l*F*1152;
    const float* sc = (l > 0) ? (scshb + (size_t)(l-1)*256) : scshb;
    float* st = (l < 2) ? (stats + (size_t)l*256) : stats;
    int mode = (l == 2) ? 1 : 0;
    for (int tb0 = 0; tb0 < 9; tb0 += ntab) {
      int nt = 9 - tb0; if (nt > ntab) nt = ntab;
      k_gemmY<<<gemmBlocks, 256, 0, stream>>>(x, cbuf, sc, WB, Yb, l == 0,
                                              tb0*8, (tb0 + nt)*8, tb0);
      int first = (tb0 == 0);
      int last  = (tb0 + nt == 9);
      k_aggC<<<aggBlocks, 256, 0, stream>>>(Yb, off, cnt, csr, bias[l], cbuf,
                                            out, out, st, tb0, nt, mode, first, last);
    }
    if (l < 2)
      k_scsh<<<1, 128, 0, stream>>>(st, gamma[l], beta[l], scshb + (size_t)l*256);
  }
}

// Round 12
// 965.803 us; speedup vs baseline: 1.4336x; 1.4336x over previous
//
#include <hip/hip_runtime.h>

#define NN 100000
#define EE 1600000
#define RRR 8
#define NSEG (NN*RRR)
#define F 128
#define KDIM 1152          // 8 relations * 128 + self(root) 128
#define NKT 36             // KDIM/32
#define BNEPS 1e-5f

typedef __attribute__((ext_vector_type(8))) short bf16x8;
typedef __attribute__((ext_vector_type(8))) unsigned short u16x8;
typedef __attribute__((ext_vector_type(4))) float f32x4;

static __device__ __forceinline__ unsigned short bf16r(float f) {
  unsigned u = __float_as_uint(f);
  u += 0x7fffu + ((u >> 16) & 1u);
  return (unsigned short)(u >> 16);
}
static __device__ __forceinline__ float b2f(unsigned short s) {
  return __uint_as_float((unsigned)s << 16);
}

// ------------------- preprocessing -------------------
// fused: bf16 convert of x  +  per-(dst,rel) segment count
__global__ __launch_bounds__(256) void k_precnt(const float* __restrict__ x,
    unsigned short* __restrict__ xb, const int* __restrict__ dst,
    const int* __restrict__ et, unsigned* __restrict__ cnt) {
  int idx = blockIdx.x*256 + threadIdx.x;
  if (idx < NN*32) {
    float4 v = ((const float4*)x)[idx];
    ushort4 o;
    o.x = bf16r(v.x); o.y = bf16r(v.y); o.z = bf16r(v.z); o.w = bf16r(v.w);
    ((ushort4*)xb)[idx] = o;
  }
  if (idx < EE)
    atomicAdd(&cnt[dst[idx]*RRR + et[idx]], 1u);
}

__global__ void k_scan1(const unsigned* __restrict__ cnt, unsigned* __restrict__ off,
                        unsigned* __restrict__ bsum) {
  __shared__ unsigned s[256];
  int t = threadIdx.x;
  int base = blockIdx.x*2048 + t*8;
  unsigned loc[8];
  unsigned tot = 0;
#pragma unroll
  for (int j = 0; j < 8; j++) {
    unsigned v = (base+j < NSEG) ? cnt[base+j] : 0u;
    loc[j] = tot;
    tot += v;
  }
  s[t] = tot;
  __syncthreads();
  for (int d = 1; d < 256; d <<= 1) {
    unsigned v = (t >= d) ? s[t-d] : 0u;
    __syncthreads();
    s[t] += v;
    __syncthreads();
  }
  unsigned tbase = s[t] - tot;
#pragma unroll
  for (int j = 0; j < 8; j++)
    if (base+j < NSEG) off[base+j] = tbase + loc[j];
  if (t == 255) bsum[blockIdx.x] = s[255];
}

__global__ void k_scan2(unsigned* bsum, int nb) {
  __shared__ unsigned s[512];
  int t = threadIdx.x;
  unsigned v = (t < nb) ? bsum[t] : 0u;
  s[t] = v;
  __syncthreads();
  for (int d = 1; d < 512; d <<= 1) {
    unsigned u = (t >= d) ? s[t-d] : 0u;
    __syncthreads();
    s[t] += u;
    __syncthreads();
  }
  if (t < nb) bsum[t] = (t == 0) ? 0u : s[t-1];
}

__global__ void k_scan3(unsigned* off, const unsigned* __restrict__ bsum) {
  int i = blockIdx.x*256 + threadIdx.x;
  if (i < NSEG) off[i] += bsum[i >> 11];
}

// fill: off becomes segment END; start = off - cnt
__global__ void k_fill(const int* __restrict__ src, const int* __restrict__ dst,
                       const int* __restrict__ et, unsigned* __restrict__ off,
                       int* __restrict__ csr) {
  int e = blockIdx.x*256 + threadIdx.x;
  if (e < EE) {
    int seg = dst[e]*RRR + et[e];
    unsigned pos = atomicAdd(&off[seg], 1u);
    csr[pos] = src[e];
  }
}

// All 3 layers' weights in B-fragment layout; block(0,0,0) zeroes stats (512 f).
// WB3[l][((kt*8 + ct)*64 + lane)*8 + j] = Wcat_l[k][o],
//   k = kt*32 + (lane>>4)*8 + j,  o = ct*16 + (lane&15)
__global__ void k_makeW3(const float* __restrict__ b1, const float* __restrict__ c1,
                         const float* __restrict__ r1, const float* __restrict__ b2,
                         const float* __restrict__ c2, const float* __restrict__ r2,
                         const float* __restrict__ b3, const float* __restrict__ c3,
                         const float* __restrict__ r3, unsigned short* __restrict__ WB3,
                         float* __restrict__ stats) {
  int kt = blockIdx.x, ct = blockIdx.y, l = blockIdx.z;
  int lane = threadIdx.x;
  if (kt == 0 && ct == 0 && l == 0) {
#pragma unroll
    for (int j = 0; j < 8; j++) stats[lane*8 + j] = 0.f;
  }
  const float* basis = (l == 0) ? b1 : (l == 1) ? b2 : b3;
  const float* comp  = (l == 0) ? c1 : (l == 1) ? c2 : c3;
  const float* root  = (l == 0) ? r1 : (l == 1) ? r2 : r3;
  int o = ct*16 + (lane & 15);
  int kbase = kt*32 + (lane >> 4)*8;
  unsigned short v[8];
#pragma unroll
  for (int j = 0; j < 8; j++) {
    int k = kbase + j;
    float val;
    if (k < 1024) {
      int r = k >> 7, i = k & 127;
      val = 0.f;
#pragma unroll
      for (int bb = 0; bb < 8; bb++)
        val += comp[r*8+bb] * basis[(bb*F + i)*F + o];
    } else {
      val = root[(k - 1024)*F + o];
    }
    v[j] = bf16r(val);
  }
  unsigned short* dstp = WB3 + (size_t)l*KDIM*F + ((size_t)(kt*8 + ct)*64 + lane)*8;
#pragma unroll
  for (int j = 0; j < 8; j++) dstp[j] = v[j];
}

// ------------------- fused layer: gather->LDS A-tile -> MFMA -> epilogue ------
// Block = 16 output rows. Phase 1: group g (16 lanes) gathers row g's 8
// relation-means (2-interleaved walk) + self, BN+LeakyReLU inline, writes
// bf16 A-fragments to LDS (XOR-swizzled). Phase 2: wave w computes ct=2w,2w+1.
// mode 0: bf16 h out + BN stats. mode 1: row L2-norm -> f32 out.
__global__ __launch_bounds__(256) void k_fused(const unsigned short* __restrict__ hb,
    const unsigned* __restrict__ off, const unsigned* __restrict__ cnt,
    const int* __restrict__ csr, const unsigned short* __restrict__ WB,
    const float* __restrict__ bias, const float* __restrict__ statsIn,
    const float* __restrict__ gamma, const float* __restrict__ beta, int hasBN,
    unsigned short* __restrict__ houtb, float* __restrict__ fout,
    float* __restrict__ statsOut, int mode) {
  __shared__ unsigned short lA[NKT*64*8];    // 36864 B A-tile (fragment order)
  __shared__ float s_sum[128], s_sq[128];
  __shared__ float rowss[16];
  int t = threadIdx.x;
  if (mode == 0) { if (t < 128) { s_sum[t] = 0.f; s_sq[t] = 0.f; } }
  else if (t < 16) rowss[t] = 0.f;

  int g = t >> 4, sl = t & 15, c8 = sl*8;
  int node = blockIdx.x*16 + g;     // NN = 6250*16 exactly, no tail

  float sc[8], sh[8];
  float lk = hasBN ? 0.1f : 1.0f;
  if (hasBN) {
    const float invN = 1.f/(float)NN;
#pragma unroll
    for (int u = 0; u < 8; u++) {
      float m = statsIn[c8+u]*invN;
      float var = statsIn[128+c8+u]*invN - m*m;
      float rs = rsqrtf(var + BNEPS);
      float gg = gamma[c8+u]*rs;
      sc[u] = gg;
      sh[u] = beta[c8+u] - m*gg;
    }
  } else {
#pragma unroll
    for (int u = 0; u < 8; u++) { sc[u] = 1.f; sh[u] = 0.f; }
  }

  // LDS position for this (row g, channel slice sl): chunk kt = base + (sl>>2),
  // lane pos = (g ^ swz) + 16*(sl&3), swz = ((kt&1)<<2)|(sl&3).
  int ktl = sl >> 2, kgl = sl & 3;
  int swz = ((ktl & 1) << 2) | kgl;
  int rowp = (g ^ swz) + 16*kgl;
  const unsigned short* hc = hb + c8;

#pragma unroll
  for (int rp = 0; rp < 4; rp++) {
    int s0 = node*RRR + 2*rp;
    unsigned cA = cnt[s0], cB = cnt[s0+1];
    unsigned bA = off[s0] - cA, bB = off[s0+1] - cB;
    float aA[8], aB[8];
#pragma unroll
    for (int u = 0; u < 8; u++) { aA[u] = 0.f; aB[u] = 0.f; }
    unsigned jA = 0, jB = 0;
    while (jA < cA || jB < cB) {
      unsigned nA = cA - jA; if (nA > 2) nA = 2;
      unsigned nB = cB - jB; if (nB > 2) nB = 2;
      int i0 = 0, i1 = 0, i2 = 0, i3 = 0;
      if (nA > 0) i0 = csr[bA + jA];
      if (nA > 1) i1 = csr[bA + jA + 1];
      if (nB > 0) i2 = csr[bB + jB];
      if (nB > 1) i3 = csr[bB + jB + 1];
      if (nA > 0) {
        u16x8 v = *(const u16x8*)&hc[(size_t)i0*F];
#pragma unroll
        for (int u = 0; u < 8; u++) { float z = b2f(v[u])*sc[u]+sh[u]; aA[u] += fmaxf(z, lk*z); }
      }
      if (nA > 1) {
        u16x8 v = *(const u16x8*)&hc[(size_t)i1*F];
#pragma unroll
        for (int u = 0; u < 8; u++) { float z = b2f(v[u])*sc[u]+sh[u]; aA[u] += fmaxf(z, lk*z); }
      }
      if (nB > 0) {
        u16x8 v = *(const u16x8*)&hc[(size_t)i2*F];
#pragma unroll
        for (int u = 0; u < 8; u++) { float z = b2f(v[u])*sc[u]+sh[u]; aB[u] += fmaxf(z, lk*z); }
      }
      if (nB > 1) {
        u16x8 v = *(const u16x8*)&hc[(size_t)i3*F];
#pragma unroll
        for (int u = 0; u < 8; u++) { float z = b2f(v[u])*sc[u]+sh[u]; aB[u] += fmaxf(z, lk*z); }
      }
      jA += nA; jB += nB;
    }
    float ivA = cA ? 1.f/(float)cA : 0.f;
    float ivB = cB ? 1.f/(float)cB : 0.f;
    u16x8 oA, oB;
#pragma unroll
    for (int u = 0; u < 8; u++) { oA[u] = bf16r(aA[u]*ivA); oB[u] = bf16r(aB[u]*ivB); }
    *(u16x8*)&lA[((2*rp*4 + ktl)*64 + rowp)*8] = oA;
    *(u16x8*)&lA[(((2*rp+1)*4 + ktl)*64 + rowp)*8] = oB;
  }
  {  // self row (BN'd input)
    u16x8 v = *(const u16x8*)&hc[(size_t)node*F];
    u16x8 os;
#pragma unroll
    for (int u = 0; u < 8; u++) {
      float z = b2f(v[u])*sc[u] + sh[u];
      os[u] = bf16r(fmaxf(z, lk*z));
    }
    *(u16x8*)&lA[((32 + ktl)*64 + rowp)*8] = os;
  }
  __syncthreads();

  // ---- phase 2: MFMA, wave w owns ct = 2w, 2w+1 ----
  int wave = t >> 6, lane = t & 63;
  int rlo = lane & 15, kg = lane >> 4;
  int ct0 = wave*2;
  f32x4 acc0 = (f32x4){0.f,0.f,0.f,0.f};
  f32x4 acc1 = (f32x4){0.f,0.f,0.f,0.f};
#pragma unroll 4
  for (int kt = 0; kt < NKT; kt++) {
    int sw = ((kt & 1) << 2) | kg;
    bf16x8 a = *(const bf16x8*)&lA[((size_t)kt*64 + ((rlo ^ sw) + 16*kg))*8];
    const unsigned short* bp = WB + ((size_t)(kt*8 + ct0)*64 + lane)*8;
    bf16x8 b0 = *(const bf16x8*)bp;
    bf16x8 b1 = *(const bf16x8*)(bp + 512);
    acc0 = __builtin_amdgcn_mfma_f32_16x16x32_bf16(a, b0, acc0, 0, 0, 0);
    acc1 = __builtin_amdgcn_mfma_f32_16x16x32_bf16(a, b1, acc1, 0, 0, 0);
  }

  float bv0 = bias[ct0*16 + rlo];
  float bv1 = bias[(ct0+1)*16 + rlo];
  int rbase = blockIdx.x*16;

  if (mode == 0) {
    float psum0 = 0.f, psq0 = 0.f, psum1 = 0.f, psq1 = 0.f;
#pragma unroll
    for (int i = 0; i < 4; i++) {
      int row = rbase + kg*4 + i;
      float y0 = acc0[i] + bv0;
      float y1 = acc1[i] + bv1;
      unsigned short* orow = houtb + (size_t)row*F;
      orow[ct0*16 + rlo]     = bf16r(y0);
      orow[(ct0+1)*16 + rlo] = bf16r(y1);
      psum0 += y0; psq0 += y0*y0;
      psum1 += y1; psq1 += y1*y1;
    }
    // reduce over kg (4 lanes share channel)
    psum0 += __shfl_xor(psum0, 16, 64); psum0 += __shfl_xor(psum0, 32, 64);
    psq0  += __shfl_xor(psq0 , 16, 64); psq0  += __shfl_xor(psq0 , 32, 64);
    psum1 += __shfl_xor(psum1, 16, 64); psum1 += __shfl_xor(psum1, 32, 64);
    psq1  += __shfl_xor(psq1 , 16, 64); psq1  += __shfl_xor(psq1 , 32, 64);
    if (lane < 16) {
      atomicAdd(&s_sum[ct0*16 + rlo], psum0);
      atomicAdd(&s_sq [ct0*16 + rlo], psq0);
      atomicAdd(&s_sum[(ct0+1)*16 + rlo], psum1);
      atomicAdd(&s_sq [(ct0+1)*16 + rlo], psq1);
    }
    __syncthreads();
    if (t < 128) {
      atomicAdd(&statsOut[t],       s_sum[t]);
      atomicAdd(&statsOut[128 + t], s_sq[t]);
    }
  } else {
    float y0v[4], y1v[4], ssp[4];
#pragma unroll
    for (int i = 0; i < 4; i++) {
      y0v[i] = acc0[i] + bv0;
      y1v[i] = acc1[i] + bv1;
      ssp[i] = y0v[i]*y0v[i] + y1v[i]*y1v[i];
    }
#pragma unroll
    for (int i = 0; i < 4; i++) {
      ssp[i] += __shfl_xor(ssp[i], 1, 64);
      ssp[i] += __shfl_xor(ssp[i], 2, 64);
      ssp[i] += __shfl_xor(ssp[i], 4, 64);
      ssp[i] += __shfl_xor(ssp[i], 8, 64);
    }
    if (rlo == 0) {
#pragma unroll
      for (int i = 0; i < 4; i++)
        atomicAdd(&rowss[kg*4 + i], ssp[i]);
    }
    __syncthreads();
#pragma unroll
    for (int i = 0; i < 4; i++) {
      int row = rbase + kg*4 + i;
      float inv = 1.f / fmaxf(sqrtf(rowss[kg*4 + i]), 1e-12f);
      float* orow = fout + (size_t)row*F;
      orow[ct0*16 + rlo]     = y0v[i]*inv;
      orow[(ct0+1)*16 + rlo] = y1v[i]*inv;
    }
  }
}

// ------------------- host launcher -------------------
extern "C" void kernel_launch(void* const* d_in, const int* in_sizes, int n_in,
                              void* d_out, int out_size, void* d_ws, size_t ws_size,
                              hipStream_t stream) {
  const float* x      = (const float*)d_in[0];
  const int*   ei     = (const int*)d_in[1];
  const int*   etp    = (const int*)d_in[2];
  const float* basis[3] = {(const float*)d_in[3], (const float*)d_in[7],  (const float*)d_in[11]};
  const float* comp[3]  = {(const float*)d_in[4], (const float*)d_in[8],  (const float*)d_in[12]};
  const float* root[3]  = {(const float*)d_in[5], (const float*)d_in[9],  (const float*)d_in[13]};
  const float* bias[3]  = {(const float*)d_in[6], (const float*)d_in[10], (const float*)d_in[14]};
  const float* gamma[2] = {(const float*)d_in[15], (const float*)d_in[17]};
  const float* beta[2]  = {(const float*)d_in[16], (const float*)d_in[18]};
  const int* srcv = ei;
  const int* dstv = ei + EE;
  float* out = (float*)d_out;

  char* w = (char*)d_ws;
  size_t p = 0;
  auto take = [&](size_t bytes) -> void* {
    void* q = w + p;
    p = (p + bytes + 255) & ~(size_t)255;
    return q;
  };
  unsigned* cnt   = (unsigned*)take((size_t)NSEG*4);
  unsigned* off   = (unsigned*)take((size_t)NSEG*4);
  int*      csr   = (int*)     take((size_t)EE*4);
  unsigned* bsum  = (unsigned*)take(1024*4);
  unsigned short* WB3 = (unsigned short*)take((size_t)3*KDIM*F*2);
  float*    stats = (float*)   take(512*4);
  unsigned short* xb    = (unsigned short*)take((size_t)NN*F*2);
  unsigned short* cbuf0 = (unsigned short*)take((size_t)NN*F*2);
  unsigned short* cbuf1 = (unsigned short*)take((size_t)NN*F*2);
  (void)ws_size;   // total ~91 MB, well under workspace

  // -------- preprocessing --------
  hipMemsetAsync(cnt, 0, (size_t)NSEG*4, stream);
  k_precnt<<<12500, 256, 0, stream>>>(x, xb, dstv, etp, cnt);
  int nb1 = (NSEG + 2047)/2048;
  k_scan1<<<nb1, 256, 0, stream>>>(cnt, off, bsum);
  k_scan2<<<1, 512, 0, stream>>>(bsum, nb1);
  k_scan3<<<(NSEG+255)/256, 256, 0, stream>>>(off, bsum);
  k_fill<<<(EE+255)/256, 256, 0, stream>>>(srcv, dstv, etp, off, csr);
  dim3 gw(NKT, 8, 3);
  k_makeW3<<<gw, 64, 0, stream>>>(basis[0], comp[0], root[0],
                                  basis[1], comp[1], root[1],
                                  basis[2], comp[2], root[2], WB3, stats);

  // -------- 3 fused layers --------
  int NB = NN/16;   // 6250
  // layer 1: input xb (no BN), out cbuf0 + stats[0:256]
  k_fused<<<NB, 256, 0, stream>>>(xb, off, cnt, csr, WB3, bias[0],
                                  stats, gamma[0], beta[0], 0,
                                  cbuf0, out, stats, 0);
  // layer 2: input cbuf0 (BN w/ stats[0:256]), out cbuf1 + stats[256:512]
  k_fused<<<NB, 256, 0, stream>>>(cbuf0, off, cnt, csr, WB3 + (size_t)KDIM*F, bias[1],
                                  stats, gamma[0], beta[0], 1,
                                  cbuf1, out, stats + 256, 0);
  // layer 3: input cbuf1 (BN w/ stats[256:512]), L2-norm -> out
  k_fused<<<NB, 256, 0, stream>>>(cbuf1, off, cnt, csr, WB3 + (size_t)2*KDIM*F, bias[2],
                                  stats + 256, gamma[1], beta[1], 1,
                                  cbuf0, out, stats, 1);
}